// Round 11
// baseline (682.050 us; speedup 1.0000x reference)
//
#include <hip/hip_runtime.h>
#include <math.h>

#define HW 512
#define KSZ 576                    // C*K*K = 64*9
#define XF_OFF (64 * KSZ)          // wq = 36864 elements, xf follows
#define NPART 1024                 // one partial slot per block
#define NBLK 1024
// partials live in out[XF_OFF + j*NPART + b] : written phase 1 (unique
// writer), read phase 2a, overwritten by phase 3b. No init needed.
// ws layout (32-bit words):
#define WS_BAR   0                 // unsigned barrier counter (memset to 0)
#define WS_WMAX  64                // 576 floats
#define WS_SCALE 640               // 576
#define WS_RX    1216              // 576
#define WS_RW    1792              // 576
#define WS_SX    2368
#define WS_SW    2369

__device__ __forceinline__ void gridbar(unsigned* bar, unsigned target) {
  __syncthreads();
  __threadfence();                                   // release: publish writes
  if (threadIdx.x == 0) {
    __hip_atomic_fetch_add(bar, 1u, __ATOMIC_ACQ_REL, __HIP_MEMORY_SCOPE_AGENT);
    int spins = 0;
    while (__hip_atomic_load(bar, __ATOMIC_ACQUIRE, __HIP_MEMORY_SCOPE_AGENT) <
               target && spins < (1 << 19)) {        // bounded: no hang
      ++spins;
      __builtin_amdgcn_s_sleep(2);
    }
  }
  __threadfence();                                   // acquire: drop stale lines
  __syncthreads();
}

__global__ __launch_bounds__(256, 4) void k_all(const float* __restrict__ in,
                                                const float* __restrict__ wgt,
                                                float* __restrict__ ws,
                                                float* __restrict__ out) {
  __shared__ float ldsT[64][68];    // transpose tile / early scratch
  __shared__ float rq_s[KSZ];
  __shared__ float red4[4];
  unsigned* bar = reinterpret_cast<unsigned*>(ws) + WS_BAR;
  const int t = threadIdx.x;
  const int b = blockIdx.x;         // 1024 blocks, all co-resident (4/CU)
  const int h0 = (b >> 3) << 2;     // 128 h-quads x 4 rows
  const int w0 = (b & 7) << 6;
  const int c = t >> 2;             // 4 threads per channel
  const int fi = t & 3;

  // ---- load tile into registers ONCE: 4 rows x 16 w for channel c ----
  const float4* ibase = reinterpret_cast<const float4*>(
      in + (size_t)c * HW * HW + (size_t)h0 * HW + w0);
  float4 v[16];
#pragma unroll
  for (int r = 0; r < 4; ++r)
#pragma unroll
    for (int k = 0; k < 4; ++k) v[r * 4 + k] = ibase[r * 128 + fi + 4 * k];

  // ---- phase 1: per-channel maxima, 3 w-variants (+row-excluded at edges) ----
  const bool topB = (b < 8);        // tile contains row 0
  const bool botB = (b >= NBLK - 8);// tile contains row 511
  float aAll = 0.f, aNo0 = 0.f, aNoL = 0.f;
  float bAll = 0.f, bNo0 = 0.f, bNoL = 0.f;
#pragma unroll
  for (int r = 0; r < 4; ++r) {
#pragma unroll
    for (int k = 0; k < 4; ++k) {
      const float4 q = v[r * 4 + k];
      const float e0 = fabsf(q.x), e1 = fabsf(q.y), e2 = fabsf(q.z), e3 = fabsf(q.w);
      const float m4 = fmaxf(fmaxf(e0, e1), fmaxf(e2, e3));
      const float n0 = (w0 == 0 && fi == 0 && k == 0) ? fmaxf(fmaxf(e1, e2), e3) : m4;
      const float nL = (w0 == 448 && fi == 3 && k == 3) ? fmaxf(fmaxf(e0, e1), e2) : m4;
      aAll = fmaxf(aAll, m4); aNo0 = fmaxf(aNo0, n0); aNoL = fmaxf(aNoL, nL);
      if (!((topB && r == 0) || (botB && r == 3))) {
        bAll = fmaxf(bAll, m4); bNo0 = fmaxf(bNo0, n0); bNoL = fmaxf(bNoL, nL);
      }
    }
  }
#pragma unroll
  for (int m = 1; m <= 2; m <<= 1) {
    aAll = fmaxf(aAll, __shfl_xor(aAll, m));
    aNo0 = fmaxf(aNo0, __shfl_xor(aNo0, m));
    aNoL = fmaxf(aNoL, __shfl_xor(aNoL, m));
    bAll = fmaxf(bAll, __shfl_xor(bAll, m));
    bNo0 = fmaxf(bNo0, __shfl_xor(bNo0, m));
    bNoL = fmaxf(bNoL, __shfl_xor(bNoL, m));
  }
  float* P = out + XF_OFF;
  if (fi == 0) {
    const float aV[3] = {aNoL, aAll, aNo0};   // kw=0: w<=510, 1: all, 2: w>=1
    const float bV[3] = {bNoL, bAll, bNo0};
#pragma unroll
    for (int kv = 0; kv < 3; ++kv) {
      P[(c * 9 + 0 + kv) * NPART + b] = botB ? bV[kv] : aV[kv];  // kh=0: h<=510
      P[(c * 9 + 3 + kv) * NPART + b] = aV[kv];                  // kh=1
      P[(c * 9 + 6 + kv) * NPART + b] = topB ? bV[kv] : aV[kv];  // kh=2: h>=1
    }
  }
  // blocks 576..639 additionally: wmax[j] for 9 columns each
  if (b >= 576 && b < 640) {
    float* sh = &ldsT[0][0];
    const int j0 = (b - 576) * 9;
    for (int idx = t; idx < 576; idx += 256) {
      const int co = idx / 9, jj = idx - co * 9;
      sh[idx] = fabsf(wgt[co * KSZ + j0 + jj]);
    }
    __syncthreads();
    if (t < 9) {
      float wm = 0.f;
      for (int co = 0; co < 64; ++co) wm = fmaxf(wm, sh[co * 9 + t]);
      ws[WS_WMAX + j0 + t] = wm;
    }
  }

  gridbar(bar, NBLK);        // partials + wmax visible

  // ---- phase 2a: blocks 0..575 reduce one column -> scale, rx, rw ----
  if (b < 576) {
    const float4* pc = reinterpret_cast<const float4*>(P + (size_t)b * NPART);
    const float4 q = pc[t];
    float m = fmaxf(fmaxf(q.x, q.y), fmaxf(q.z, q.w));
#pragma unroll
    for (int s = 32; s >= 1; s >>= 1) m = fmaxf(m, __shfl_xor(m, s));
    if ((t & 63) == 0) red4[t >> 6] = m;
    __syncthreads();
    if (t == 0) {
      const float act = fmaxf(fmaxf(red4[0], red4[1]), fmaxf(red4[2], red4[3]));
      const float wm = ws[WS_WMAX + b];
      float scale = sqrtf(act) / sqrtf(wm);   // alpha = 0.5
      if (scale == 0.f) scale = 1.f;
      ws[WS_SCALE + b] = scale;
      ws[WS_RX + b] = act / scale;            // column max of |x/scale|
      ws[WS_RW + b] = wm * scale;
    }
  }

  gridbar(bar, 2 * NBLK);    // scale/rx/rw visible

  // ---- phase 2b: block 0 -> sx, sw ----
  if (b == 0) {
    float rx = 0.f, rw = 0.f;
#pragma unroll
    for (int rep = 0; rep < 3; ++rep) {
      const int j = t + rep * 256;
      if (j < KSZ) { rx = fmaxf(rx, ws[WS_RX + j]); rw = fmaxf(rw, ws[WS_RW + j]); }
    }
#pragma unroll
    for (int s = 32; s >= 1; s >>= 1) {
      rx = fmaxf(rx, __shfl_xor(rx, s));
      rw = fmaxf(rw, __shfl_xor(rw, s));
    }
    float* sh = &ldsT[0][0];
    if ((t & 63) == 0) { sh[(t >> 6) * 2] = rx; sh[(t >> 6) * 2 + 1] = rw; }
    __syncthreads();
    if (t == 0) {
      const float mx = fmaxf(fmaxf(sh[0], sh[2]), fmaxf(sh[4], sh[6]));
      const float mw = fmaxf(fmaxf(sh[1], sh[3]), fmaxf(sh[5], sh[7]));
      ws[WS_SX] = (mx > 0.f) ? (mx / 127.f) : 1.f;
      ws[WS_SW] = (mw > 0.f) ? (mw / 127.f) : 1.f;
    }
  }

  gridbar(bar, 3 * NBLK);    // sx, sw visible

  // ---- phase 3a: blocks 0..63 write wq row co=b ----
  const float sx = ws[WS_SX];
  if (b < 64) {
    const float sw = ws[WS_SW];
#pragma unroll
    for (int rep = 0; rep < 3; ++rep) {
      const int j = t + rep * 256;
      if (j < KSZ) {
        const int cc = j / 9, r = j - cc * 9;
        float u = (wgt[b * KSZ + j] * ws[WS_SCALE + j]) / sw;
        u = fminf(fmaxf(u, -127.f), 127.f);
        out[b * KSZ + r * 64 + cc] = rintf(u) * sw;
      }
    }
  }

  // ---- phase 3b: quantize from held registers + LDS transpose -> xf ----
#pragma unroll
  for (int rep = 0; rep < 3; ++rep) {
    const int j = t + rep * 256;
    if (j < KSZ) rq_s[j] = 1.f / (ws[WS_SCALE + j] * sx);
  }
  __syncthreads();
  float rq[9];
#pragma unroll
  for (int jj = 0; jj < 9; ++jj) rq[jj] = rq_s[c * 9 + jj];

#pragma unroll
  for (int r = 0; r < 4; ++r) {
    const int h = h0 + r;
    const bool hb = (h == 0) || (h == 511);
#pragma unroll
    for (int k = 0; k < 4; ++k) {
      const float4 q = v[r * 4 + k];
      const int f4 = fi + 4 * k;
      const float vv[4] = {q.x, q.y, q.z, q.w};
#pragma unroll
      for (int i = 0; i < 4; ++i) {
        const int wl = f4 * 4 + i;
        const int w = w0 + wl;
        const float x = vv[i];
        float qs = 0.f;
#pragma unroll
        for (int jj = 0; jj < 9; ++jj) qs += rintf(x * rq[jj]);  // exact int sum
        if (hb || (w == 0) || (w == 511)) {                      // rare fix-up
          const bool hok0 = (h <= 510), hok2 = (h >= 1);
          const bool wok0 = (w <= 510), wok2 = (w >= 1);
          const bool ok[9] = {hok0 && wok0, hok0, hok0 && wok2,
                              wok0,         true, wok2,
                              hok2 && wok0, hok2, hok2 && wok2};
          qs = 0.f;
#pragma unroll
          for (int jj = 0; jj < 9; ++jj) {
            const float u2 = fminf(fmaxf(x * rq[jj], -127.f), 127.f);
            qs += ok[jj] ? rintf(u2) : 0.f;
          }
        }
        ldsT[wl][c] = qs * sx;
      }
    }
    __syncthreads();
    float4* ob = reinterpret_cast<float4*>(
        out + XF_OFF + ((size_t)h * HW + w0) * 64);
#pragma unroll
    for (int k = 0; k < 4; ++k) {
      const int idx4 = k * 256 + t;
      const int lw = idx4 >> 4, lc4 = idx4 & 15;
      ob[idx4] = *reinterpret_cast<const float4*>(&ldsT[lw][lc4 * 4]);
    }
    __syncthreads();                       // ldsT free for next row
  }
}

extern "C" void kernel_launch(void* const* d_in, const int* in_sizes, int n_in,
                              void* d_out, int out_size, void* d_ws, size_t ws_size,
                              hipStream_t stream) {
  (void)in_sizes; (void)n_in; (void)out_size; (void)ws_size;
  const float* in = reinterpret_cast<const float*>(d_in[0]);   // (1,64,512,512)
  const float* wgt = reinterpret_cast<const float*>(d_in[1]);  // (64,64,3,3)
  float* ws = reinterpret_cast<float*>(d_ws);
  float* out = reinterpret_cast<float*>(d_out);                // wq | xf

  (void)hipMemsetAsync(d_ws, 0, 256, stream);   // reset barrier counter
  k_all<<<dim3(NBLK), dim3(256), 0, stream>>>(in, wgt, ws, out);
}

// Round 12
// 212.187 us; speedup vs baseline: 3.2144x; 3.2144x over previous
//
#include <hip/hip_runtime.h>
#include <math.h>

#define HW 512
#define KSZ 576                    // C*K*K = 64*9
#define XF_OFF (64 * KSZ)          // wq = 36864 elements, xf follows
#define NBLK 1024
// ws layout (32-bit words). memset zeroes words [0, 640) each launch.
#define WS_BAR   0                 // barrier counter (int)
#define WS_ACT   64                // 576 float-bit maxima (atomic_fetch_max)
#define WS_WMAX  640               // 576 floats (unique writer per slot)

__global__ __launch_bounds__(256, 4) void k_all(const float* __restrict__ in,
                                                const float* __restrict__ wgt,
                                                float* __restrict__ ws,
                                                float* __restrict__ out) {
  __shared__ float ldsT[64][68];    // transpose tile / early scratch
  __shared__ float rq_s[KSZ];
  __shared__ float red[4][2];
  __shared__ float s_sx, s_sw;
  int* wsI = reinterpret_cast<int*>(ws);
  const int t = threadIdx.x;
  const int b = blockIdx.x;         // 1024 blocks, co-resident (4/CU)
  const int h0 = (b >> 3) << 2;     // 128 h-quads x 4 rows
  const int w0 = (b & 7) << 6;
  const int c = t >> 2;             // 4 threads per channel
  const int fi = t & 3;

  // ---- load tile into registers: 4 rows x 16 w for channel c ----
  const float4* ibase = reinterpret_cast<const float4*>(
      in + (size_t)c * HW * HW + (size_t)h0 * HW + w0);
  float4 v[16];
#pragma unroll
  for (int r = 0; r < 4; ++r)
#pragma unroll
    for (int k = 0; k < 4; ++k) v[r * 4 + k] = ibase[r * 128 + fi + 4 * k];

  // ---- phase 1: per-channel 9-region maxima (w-variants; row-excluded at edges) ----
  const bool topB = (b < 8);          // tile contains row 0
  const bool botB = (b >= NBLK - 8);  // tile contains row 511
  float aAll = 0.f, aNo0 = 0.f, aNoL = 0.f;
  float bAll = 0.f, bNo0 = 0.f, bNoL = 0.f;
#pragma unroll
  for (int r = 0; r < 4; ++r) {
#pragma unroll
    for (int k = 0; k < 4; ++k) {
      const float4 q = v[r * 4 + k];
      const float e0 = fabsf(q.x), e1 = fabsf(q.y), e2 = fabsf(q.z), e3 = fabsf(q.w);
      const float m4 = fmaxf(fmaxf(e0, e1), fmaxf(e2, e3));
      const float n0 = (w0 == 0 && fi == 0 && k == 0) ? fmaxf(fmaxf(e1, e2), e3) : m4;
      const float nL = (w0 == 448 && fi == 3 && k == 3) ? fmaxf(fmaxf(e0, e1), e2) : m4;
      aAll = fmaxf(aAll, m4); aNo0 = fmaxf(aNo0, n0); aNoL = fmaxf(aNoL, nL);
      if (!((topB && r == 0) || (botB && r == 3))) {
        bAll = fmaxf(bAll, m4); bNo0 = fmaxf(bNo0, n0); bNoL = fmaxf(bNoL, nL);
      }
    }
  }
#pragma unroll
  for (int m = 1; m <= 2; m <<= 1) {
    aAll = fmaxf(aAll, __shfl_xor(aAll, m));
    aNo0 = fmaxf(aNo0, __shfl_xor(aNo0, m));
    aNoL = fmaxf(aNoL, __shfl_xor(aNoL, m));
    bAll = fmaxf(bAll, __shfl_xor(bAll, m));
    bNo0 = fmaxf(bNo0, __shfl_xor(bNo0, m));
    bNoL = fmaxf(bNoL, __shfl_xor(bNoL, m));
  }
  if (fi == 0) {
    const float aV[3] = {aNoL, aAll, aNo0};   // kw=0: w<=510, 1: all, 2: w>=1
    const float bV[3] = {bNoL, bAll, bNo0};
#pragma unroll
    for (int kv = 0; kv < 3; ++kv) {
      const float v0 = botB ? bV[kv] : aV[kv];   // kh=0: h<=510
      const float v1 = aV[kv];                   // kh=1
      const float v2 = topB ? bV[kv] : aV[kv];   // kh=2: h>=1
      __hip_atomic_fetch_max(&wsI[WS_ACT + c * 9 + 0 + kv], __float_as_int(v0),
                             __ATOMIC_RELAXED, __HIP_MEMORY_SCOPE_AGENT);
      __hip_atomic_fetch_max(&wsI[WS_ACT + c * 9 + 3 + kv], __float_as_int(v1),
                             __ATOMIC_RELAXED, __HIP_MEMORY_SCOPE_AGENT);
      __hip_atomic_fetch_max(&wsI[WS_ACT + c * 9 + 6 + kv], __float_as_int(v2),
                             __ATOMIC_RELAXED, __HIP_MEMORY_SCOPE_AGENT);
    }
  }
  // blocks 576..639: wmax[j] for 9 columns each (unique writer per slot)
  if (b >= 576 && b < 640) {
    float* sh = &ldsT[0][0];
    const int j0 = (b - 576) * 9;
    for (int idx = t; idx < 576; idx += 256) {
      const int co = idx / 9, jj = idx - co * 9;
      sh[idx] = fabsf(wgt[co * KSZ + j0 + jj]);
    }
    __syncthreads();
    if (t < 9) {
      float wm = 0.f;
      for (int co = 0; co < 64; ++co) wm = fmaxf(wm, sh[co * 9 + t]);
      __hip_atomic_store(&ws[WS_WMAX + j0 + t], wm,
                         __ATOMIC_RELAXED, __HIP_MEMORY_SCOPE_AGENT);
    }
  }

  // ---- single grid barrier: cache-neutral (no inv/wbl2; sc1 ops only) ----
  __syncthreads();
  asm volatile("s_waitcnt vmcnt(0) lgkmcnt(0)" ::: "memory");  // sc1 ops at L3
  if (t == 0) {
    __hip_atomic_fetch_add(&wsI[WS_BAR], 1, __ATOMIC_RELAXED,
                           __HIP_MEMORY_SCOPE_AGENT);
    int spins = 0;
    while (__hip_atomic_load(&wsI[WS_BAR], __ATOMIC_RELAXED,
                             __HIP_MEMORY_SCOPE_AGENT) < NBLK &&
           spins < (1 << 18)) {      // bounded: no hang
      ++spins;
      __builtin_amdgcn_s_sleep(4);
    }
  }
  __syncthreads();

  // ---- phase 2 (every block, redundant & deterministic): scales ----
  float scale_r[3];
  float rxm = 0.f, rwm = 0.f;
#pragma unroll
  for (int rep = 0; rep < 3; ++rep) {
    const int j = t + rep * 256;
    if (j < KSZ) {
      const int ai = __hip_atomic_load(&wsI[WS_ACT + j], __ATOMIC_RELAXED,
                                       __HIP_MEMORY_SCOPE_AGENT);
      const float act = __int_as_float(ai);
      const float wm = __hip_atomic_load(&ws[WS_WMAX + j], __ATOMIC_RELAXED,
                                         __HIP_MEMORY_SCOPE_AGENT);
      float scale = sqrtf(act) / sqrtf(wm);   // alpha = 0.5
      if (scale == 0.f) scale = 1.f;
      scale_r[rep] = scale;
      rxm = fmaxf(rxm, act / scale);
      rwm = fmaxf(rwm, wm * scale);
    }
  }
#pragma unroll
  for (int m = 32; m >= 1; m >>= 1) {
    rxm = fmaxf(rxm, __shfl_xor(rxm, m));
    rwm = fmaxf(rwm, __shfl_xor(rwm, m));
  }
  if ((t & 63) == 0) { red[t >> 6][0] = rxm; red[t >> 6][1] = rwm; }
  __syncthreads();
  if (t == 0) {
    float mx = red[0][0], mw = red[0][1];
    for (int i = 1; i < 4; ++i) { mx = fmaxf(mx, red[i][0]); mw = fmaxf(mw, red[i][1]); }
    s_sx = (mx > 0.f) ? (mx / 127.f) : 1.f;
    s_sw = (mw > 0.f) ? (mw / 127.f) : 1.f;
  }
  __syncthreads();
  const float sx = s_sx, sw = s_sw;
#pragma unroll
  for (int rep = 0; rep < 3; ++rep) {
    const int j = t + rep * 256;
    if (j < KSZ) rq_s[j] = 1.f / (scale_r[rep] * sx);
  }
  __syncthreads();

  // ---- wq: blocks 0..63 each write one cout row ----
  if (b < 64) {
#pragma unroll
    for (int rep = 0; rep < 3; ++rep) {
      const int j = t + rep * 256;
      if (j < KSZ) {
        const int cc = j / 9, r = j - cc * 9;
        float u = (wgt[b * KSZ + j] * scale_r[rep]) / sw;
        u = fminf(fmaxf(u, -127.f), 127.f);
        out[b * KSZ + r * 64 + cc] = rintf(u) * sw;
      }
    }
  }

  // ---- phase 3: quantize from held registers + LDS transpose -> xf ----
  float rq[9];
#pragma unroll
  for (int jj = 0; jj < 9; ++jj) rq[jj] = rq_s[c * 9 + jj];

#pragma unroll
  for (int r = 0; r < 4; ++r) {
    const int h = h0 + r;
    const bool hb = (h == 0) || (h == 511);
#pragma unroll
    for (int k = 0; k < 4; ++k) {
      const float4 q = v[r * 4 + k];
      const int f4 = fi + 4 * k;
      const float vv[4] = {q.x, q.y, q.z, q.w};
#pragma unroll
      for (int i = 0; i < 4; ++i) {
        const int wl = f4 * 4 + i;
        const int w = w0 + wl;
        const float x = vv[i];
        float qs = 0.f;
#pragma unroll
        for (int jj = 0; jj < 9; ++jj) qs += rintf(x * rq[jj]);  // exact int sum
        if (hb || (w == 0) || (w == 511)) {                      // rare fix-up
          const bool hok0 = (h <= 510), hok2 = (h >= 1);
          const bool wok0 = (w <= 510), wok2 = (w >= 1);
          const bool ok[9] = {hok0 && wok0, hok0, hok0 && wok2,
                              wok0,         true, wok2,
                              hok2 && wok0, hok2, hok2 && wok2};
          qs = 0.f;
#pragma unroll
          for (int jj = 0; jj < 9; ++jj) {
            const float u2 = fminf(fmaxf(x * rq[jj], -127.f), 127.f);
            qs += ok[jj] ? rintf(u2) : 0.f;
          }
        }
        ldsT[wl][c] = qs * sx;
      }
    }
    __syncthreads();
    float4* ob = reinterpret_cast<float4*>(
        out + XF_OFF + ((size_t)h * HW + w0) * 64);
#pragma unroll
    for (int k = 0; k < 4; ++k) {
      const int idx4 = k * 256 + t;
      const int lw = idx4 >> 4, lc4 = idx4 & 15;
      ob[idx4] = *reinterpret_cast<const float4*>(&ldsT[lw][lc4 * 4]);
    }
    __syncthreads();                       // ldsT free for next row
  }
}

extern "C" void kernel_launch(void* const* d_in, const int* in_sizes, int n_in,
                              void* d_out, int out_size, void* d_ws, size_t ws_size,
                              hipStream_t stream) {
  (void)in_sizes; (void)n_in; (void)out_size; (void)ws_size;
  const float* in = reinterpret_cast<const float*>(d_in[0]);   // (1,64,512,512)
  const float* wgt = reinterpret_cast<const float*>(d_in[1]);  // (64,64,3,3)
  float* ws = reinterpret_cast<float*>(d_ws);
  float* out = reinterpret_cast<float*>(d_out);                // wq | xf

  (void)hipMemsetAsync(d_ws, 0, 2560, stream);   // bar + act[576] = 0
  k_all<<<dim3(NBLK), dim3(256), 0, stream>>>(in, wgt, ws, out);
}

// Round 13
// 162.749 us; speedup vs baseline: 4.1908x; 1.3038x over previous
//
#include <hip/hip_runtime.h>
#include <math.h>

#define HW 512
#define KSZ 576                    // C*K*K = 64*9
#define XF_OFF (64 * KSZ)          // wq = 36864 elements, xf follows
#define NBLK 1024
// Partials P[j*NBLK + b] live in the xf region of out (scratch until phase 3
// overwrites). Unique writer per slot -> relaxed agent stores, no contention.
// ws layout (32-bit words). memset zeroes words [0, 64) each launch.
#define WS_BAR   0                 // barrier counter (int)
#define WS_WMAX  64                // 576 floats
#define WS_SCALE 640               // 576 floats
#define WS_RX    1216              // 576 floats
#define WS_RW    1792              // 576 floats

__device__ __forceinline__ void gridbar(int* bar, int target) {
  __syncthreads();
  asm volatile("s_waitcnt vmcnt(0) lgkmcnt(0)" ::: "memory");  // sc1 ops done
  if (threadIdx.x == 0) {
    __hip_atomic_fetch_add(bar, 1, __ATOMIC_RELAXED, __HIP_MEMORY_SCOPE_AGENT);
    int spins = 0;
    while (__hip_atomic_load(bar, __ATOMIC_RELAXED,
                             __HIP_MEMORY_SCOPE_AGENT) < target &&
           spins < (1 << 18)) {     // bounded: no hang
      ++spins;
      __builtin_amdgcn_s_sleep(2);
    }
  }
  __syncthreads();
}

__global__ __launch_bounds__(256, 4) void k_all(const float* __restrict__ in,
                                                const float* __restrict__ wgt,
                                                float* __restrict__ ws,
                                                float* __restrict__ out) {
  __shared__ float ldsT[64][68];    // transpose tile / early scratch
  __shared__ float rq_s[KSZ];
  __shared__ float red[4][2];
  __shared__ float s_sx, s_sw;
  int* wsI = reinterpret_cast<int*>(ws);
  float* P = out + XF_OFF;
  const int t = threadIdx.x;
  const int b = blockIdx.x;         // 1024 blocks, co-resident (4/CU)
  const int h0 = (b >> 3) << 2;     // 128 h-quads x 4 rows
  const int w0 = (b & 7) << 6;
  const int c = t >> 2;             // 4 threads per channel
  const int fi = t & 3;

  // ---- load tile: 4 rows x 16 w for channel c ----
  const float4* ibase = reinterpret_cast<const float4*>(
      in + (size_t)c * HW * HW + (size_t)h0 * HW + w0);
  float4 v[16];
#pragma unroll
  for (int r = 0; r < 4; ++r)
#pragma unroll
    for (int k = 0; k < 4; ++k) v[r * 4 + k] = ibase[r * 128 + fi + 4 * k];

  // ---- phase 1: per-channel 9-region maxima ----
  const bool topB = (b < 8);          // tile contains row 0
  const bool botB = (b >= NBLK - 8);  // tile contains row 511
  float aAll = 0.f, aNo0 = 0.f, aNoL = 0.f;
  float bAll = 0.f, bNo0 = 0.f, bNoL = 0.f;
#pragma unroll
  for (int r = 0; r < 4; ++r) {
#pragma unroll
    for (int k = 0; k < 4; ++k) {
      const float4 q = v[r * 4 + k];
      const float e0 = fabsf(q.x), e1 = fabsf(q.y), e2 = fabsf(q.z), e3 = fabsf(q.w);
      const float m4 = fmaxf(fmaxf(e0, e1), fmaxf(e2, e3));
      const float n0 = (w0 == 0 && fi == 0 && k == 0) ? fmaxf(fmaxf(e1, e2), e3) : m4;
      const float nL = (w0 == 448 && fi == 3 && k == 3) ? fmaxf(fmaxf(e0, e1), e2) : m4;
      aAll = fmaxf(aAll, m4); aNo0 = fmaxf(aNo0, n0); aNoL = fmaxf(aNoL, nL);
      if (!((topB && r == 0) || (botB && r == 3))) {
        bAll = fmaxf(bAll, m4); bNo0 = fmaxf(bNo0, n0); bNoL = fmaxf(bNoL, nL);
      }
    }
  }
#pragma unroll
  for (int m = 1; m <= 2; m <<= 1) {
    aAll = fmaxf(aAll, __shfl_xor(aAll, m));
    aNo0 = fmaxf(aNo0, __shfl_xor(aNo0, m));
    aNoL = fmaxf(aNoL, __shfl_xor(aNoL, m));
    bAll = fmaxf(bAll, __shfl_xor(bAll, m));
    bNo0 = fmaxf(bNo0, __shfl_xor(bNo0, m));
    bNoL = fmaxf(bNoL, __shfl_xor(bNoL, m));
  }
  if (fi == 0) {                    // publish 576 partials, distinct addresses
    const float aV[3] = {aNoL, aAll, aNo0};   // kw=0: w<=510, 1: all, 2: w>=1
    const float bV[3] = {bNoL, bAll, bNo0};
#pragma unroll
    for (int kv = 0; kv < 3; ++kv) {
      const float v0 = botB ? bV[kv] : aV[kv];   // kh=0: h<=510
      const float v1 = aV[kv];                   // kh=1
      const float v2 = topB ? bV[kv] : aV[kv];   // kh=2: h>=1
      __hip_atomic_store(&P[(size_t)(c * 9 + 0 + kv) * NBLK + b], v0,
                         __ATOMIC_RELAXED, __HIP_MEMORY_SCOPE_AGENT);
      __hip_atomic_store(&P[(size_t)(c * 9 + 3 + kv) * NBLK + b], v1,
                         __ATOMIC_RELAXED, __HIP_MEMORY_SCOPE_AGENT);
      __hip_atomic_store(&P[(size_t)(c * 9 + 6 + kv) * NBLK + b], v2,
                         __ATOMIC_RELAXED, __HIP_MEMORY_SCOPE_AGENT);
    }
  }
  // blocks 576..639: wmax[j] for 9 columns each (unique writer per slot)
  if (b >= 576 && b < 640) {
    float* sh = &ldsT[0][0];
    const int j0 = (b - 576) * 9;
    for (int idx = t; idx < 576; idx += 256) {
      const int co = idx / 9, jj = idx - co * 9;
      sh[idx] = fabsf(wgt[co * KSZ + j0 + jj]);
    }
    __syncthreads();
    if (t < 9) {
      float wm = 0.f;
      for (int co = 0; co < 64; ++co) wm = fmaxf(wm, sh[co * 9 + t]);
      __hip_atomic_store(&ws[WS_WMAX + j0 + t], wm,
                         __ATOMIC_RELAXED, __HIP_MEMORY_SCOPE_AGENT);
    }
  }

  gridbar(&wsI[WS_BAR], NBLK);      // partials + wmax visible (L3)

  // ---- phase 2a: blocks 0..575 reduce one column -> scale, rx, rw ----
  if (b < 576) {
    float m = 0.f;
#pragma unroll
    for (int rep = 0; rep < 4; ++rep) {
      const float pv = __hip_atomic_load(&P[(size_t)b * NBLK + rep * 256 + t],
                                         __ATOMIC_RELAXED,
                                         __HIP_MEMORY_SCOPE_AGENT);
      m = fmaxf(m, pv);
    }
#pragma unroll
    for (int s = 32; s >= 1; s >>= 1) m = fmaxf(m, __shfl_xor(m, s));
    if ((t & 63) == 0) red[t >> 6][0] = m;
    __syncthreads();
    if (t == 0) {
      const float act = fmaxf(fmaxf(red[0][0], red[1][0]),
                              fmaxf(red[2][0], red[3][0]));
      const float wm = __hip_atomic_load(&ws[WS_WMAX + b], __ATOMIC_RELAXED,
                                         __HIP_MEMORY_SCOPE_AGENT);
      float scale = sqrtf(act) / sqrtf(wm);   // alpha = 0.5
      if (scale == 0.f) scale = 1.f;
      __hip_atomic_store(&ws[WS_SCALE + b], scale, __ATOMIC_RELAXED,
                         __HIP_MEMORY_SCOPE_AGENT);
      __hip_atomic_store(&ws[WS_RX + b], act / scale, __ATOMIC_RELAXED,
                         __HIP_MEMORY_SCOPE_AGENT);
      __hip_atomic_store(&ws[WS_RW + b], wm * scale, __ATOMIC_RELAXED,
                         __HIP_MEMORY_SCOPE_AGENT);
    }
    __syncthreads();
  }

  gridbar(&wsI[WS_BAR], 2 * NBLK);  // scale/rx/rw visible

  // ---- phase 2b (every block, redundant & deterministic): sx, sw, rq ----
  float scale_r[3];
  float rxm = 0.f, rwm = 0.f;
#pragma unroll
  for (int rep = 0; rep < 3; ++rep) {
    const int j = t + rep * 256;
    if (j < KSZ) {
      scale_r[rep] = __hip_atomic_load(&ws[WS_SCALE + j], __ATOMIC_RELAXED,
                                       __HIP_MEMORY_SCOPE_AGENT);
      rxm = fmaxf(rxm, __hip_atomic_load(&ws[WS_RX + j], __ATOMIC_RELAXED,
                                         __HIP_MEMORY_SCOPE_AGENT));
      rwm = fmaxf(rwm, __hip_atomic_load(&ws[WS_RW + j], __ATOMIC_RELAXED,
                                         __HIP_MEMORY_SCOPE_AGENT));
    }
  }
#pragma unroll
  for (int m = 32; m >= 1; m >>= 1) {
    rxm = fmaxf(rxm, __shfl_xor(rxm, m));
    rwm = fmaxf(rwm, __shfl_xor(rwm, m));
  }
  if ((t & 63) == 0) { red[t >> 6][0] = rxm; red[t >> 6][1] = rwm; }
  __syncthreads();
  if (t == 0) {
    float mx = red[0][0], mw = red[0][1];
    for (int i = 1; i < 4; ++i) { mx = fmaxf(mx, red[i][0]); mw = fmaxf(mw, red[i][1]); }
    s_sx = (mx > 0.f) ? (mx / 127.f) : 1.f;
    s_sw = (mw > 0.f) ? (mw / 127.f) : 1.f;
  }
  __syncthreads();
  const float sx = s_sx, sw = s_sw;
#pragma unroll
  for (int rep = 0; rep < 3; ++rep) {
    const int j = t + rep * 256;
    if (j < KSZ) rq_s[j] = 1.f / (scale_r[rep] * sx);
  }
  __syncthreads();

  // ---- wq: blocks 0..63 each write one cout row ----
  if (b < 64) {
#pragma unroll
    for (int rep = 0; rep < 3; ++rep) {
      const int j = t + rep * 256;
      if (j < KSZ) {
        const int cc = j / 9, r = j - cc * 9;
        float u = (wgt[b * KSZ + j] * scale_r[rep]) / sw;
        u = fminf(fmaxf(u, -127.f), 127.f);
        out[b * KSZ + r * 64 + cc] = rintf(u) * sw;
      }
    }
  }

  // ---- phase 3: quantize + LDS transpose -> xf ----
  float rq[9];
#pragma unroll
  for (int jj = 0; jj < 9; ++jj) rq[jj] = rq_s[c * 9 + jj];

#pragma unroll
  for (int r = 0; r < 4; ++r) {
    const int h = h0 + r;
    const bool hb = (h == 0) || (h == 511);
#pragma unroll
    for (int k = 0; k < 4; ++k) {
      const float4 q = v[r * 4 + k];
      const int f4 = fi + 4 * k;
      const float vv[4] = {q.x, q.y, q.z, q.w};
#pragma unroll
      for (int i = 0; i < 4; ++i) {
        const int wl = f4 * 4 + i;
        const int w = w0 + wl;
        const float x = vv[i];
        float qs = 0.f;
#pragma unroll
        for (int jj = 0; jj < 9; ++jj) qs += rintf(x * rq[jj]);  // exact int sum
        if (hb || (w == 0) || (w == 511)) {                      // rare fix-up
          const bool hok0 = (h <= 510), hok2 = (h >= 1);
          const bool wok0 = (w <= 510), wok2 = (w >= 1);
          const bool ok[9] = {hok0 && wok0, hok0, hok0 && wok2,
                              wok0,         true, wok2,
                              hok2 && wok0, hok2, hok2 && wok2};
          qs = 0.f;
#pragma unroll
          for (int jj = 0; jj < 9; ++jj) {
            const float u2 = fminf(fmaxf(x * rq[jj], -127.f), 127.f);
            qs += ok[jj] ? rintf(u2) : 0.f;
          }
        }
        ldsT[wl][c] = qs * sx;
      }
    }
    __syncthreads();
    float4* ob = reinterpret_cast<float4*>(
        out + XF_OFF + ((size_t)h * HW + w0) * 64);
#pragma unroll
    for (int k = 0; k < 4; ++k) {
      const int idx4 = k * 256 + t;
      const int lw = idx4 >> 4, lc4 = idx4 & 15;
      ob[idx4] = *reinterpret_cast<const float4*>(&ldsT[lw][lc4 * 4]);
    }
    __syncthreads();                       // ldsT free for next row
  }
}

extern "C" void kernel_launch(void* const* d_in, const int* in_sizes, int n_in,
                              void* d_out, int out_size, void* d_ws, size_t ws_size,
                              hipStream_t stream) {
  (void)in_sizes; (void)n_in; (void)out_size; (void)ws_size;
  const float* in = reinterpret_cast<const float*>(d_in[0]);   // (1,64,512,512)
  const float* wgt = reinterpret_cast<const float*>(d_in[1]);  // (64,64,3,3)
  float* ws = reinterpret_cast<float*>(d_ws);
  float* out = reinterpret_cast<float*>(d_out);                // wq | xf

  (void)hipMemsetAsync(d_ws, 0, 256, stream);    // reset barrier counter
  k_all<<<dim3(NBLK), dim3(256), 0, stream>>>(in, wgt, ws, out);
}

// Round 14
// 51.926 us; speedup vs baseline: 13.1349x; 3.1342x over previous
//
#include <hip/hip_runtime.h>
#include <math.h>

#define HW 512
#define KSZ 576                     // C*K*K = 64*9
#define NCHUNK 32                   // 16-row chunks per channel
#define WS_PART 0                   // KSZ*NCHUNK floats, layout [j][chunk]
#define WS_WMAX (KSZ * NCHUNK)      // 576 floats
#define XF_OFF (64 * KSZ)           // wq = 36864 elements, xf follows

// ---------------------------------------------------------------------------
// Kernel 1 (2048 + 3 blocks): per-(channel, 16-row chunk) maxima of |input|
// for the 9 (kh,kw) validity regions -> ws[WS_PART + j*NCHUNK + chunk].
// Plain stores, every slot written every call -> no init, deterministic.
// 8 float4/thread, ~8 blocks/CU -> latency chains hidden by TLP.
// Blocks 2048..2050: wmax[j] = max_co |wgt[co,j]|.
// ---------------------------------------------------------------------------
__global__ __launch_bounds__(256) void k_pass1(const float* __restrict__ in,
                                               const float* __restrict__ wgt,
                                               float* __restrict__ ws) {
  const int t = threadIdx.x;
  if (blockIdx.x >= 2048) {                  // wmax tail blocks
    const int j = (blockIdx.x - 2048) * 256 + t;
    if (j < KSZ) {
      float wm = 0.f;
#pragma unroll 16
      for (int co = 0; co < 64; ++co) wm = fmaxf(wm, fabsf(wgt[co * KSZ + j]));
      ws[WS_WMAX + j] = wm;
    }
    return;
  }
  const int c = blockIdx.x >> 5;
  const int chunk = blockIdx.x & 31;
  const float4* base = reinterpret_cast<const float4*>(
      in + (size_t)c * HW * HW + (size_t)(chunk << 4) * HW);

  float4 v[8];
#pragma unroll
  for (int k = 0; k < 8; ++k) v[k] = base[k * 256 + t];   // 8 loads in flight

  const int col4 = t & 127;     // w-border lanes are static per thread
  const int tb = t >> 7;
  float aAll = 0.f, aNo0 = 0.f, aNoL = 0.f;   // all rows of chunk
  float bAll = 0.f, bNo0 = 0.f, bNoL = 0.f;   // excluding chunk's border row
#pragma unroll
  for (int k = 0; k < 8; ++k) {
    const float e0 = fabsf(v[k].x), e1 = fabsf(v[k].y),
                e2 = fabsf(v[k].z), e3 = fabsf(v[k].w);
    const float m4 = fmaxf(fmaxf(e0, e1), fmaxf(e2, e3));
    const float vNo0 = (col4 == 0)   ? fmaxf(fmaxf(e1, e2), e3) : m4; // excl w=0
    const float vNoL = (col4 == 127) ? fmaxf(fmaxf(e0, e1), e2) : m4; // excl w=511
    aAll = fmaxf(aAll, m4); aNo0 = fmaxf(aNo0, vNo0); aNoL = fmaxf(aNoL, vNoL);
    const int lrow = 2 * k + tb;
    const bool keep = !((chunk == 0 && lrow == 0) || (chunk == 31 && lrow == 15));
    if (keep) {
      bAll = fmaxf(bAll, m4); bNo0 = fmaxf(bNo0, vNo0); bNoL = fmaxf(bNoL, vNoL);
    }
  }
#pragma unroll
  for (int m = 32; m >= 1; m >>= 1) {
    aAll = fmaxf(aAll, __shfl_xor(aAll, m));
    aNo0 = fmaxf(aNo0, __shfl_xor(aNo0, m));
    aNoL = fmaxf(aNoL, __shfl_xor(aNoL, m));
    bAll = fmaxf(bAll, __shfl_xor(bAll, m));
    bNo0 = fmaxf(bNo0, __shfl_xor(bNo0, m));
    bNoL = fmaxf(bNoL, __shfl_xor(bNoL, m));
  }
  __shared__ float red[4][6];
  if ((t & 63) == 0) {
    const int wv = t >> 6;
    red[wv][0] = aAll; red[wv][1] = aNo0; red[wv][2] = aNoL;
    red[wv][3] = bAll; red[wv][4] = bNo0; red[wv][5] = bNoL;
  }
  __syncthreads();
  if (t == 0) {
    float r[6];
#pragma unroll
    for (int i = 0; i < 6; ++i)
      r[i] = fmaxf(fmaxf(red[0][i], red[1][i]), fmaxf(red[2][i], red[3][i]));
    // kw mapping: kw=0 -> w<=510 (NoL), kw=1 -> All, kw=2 -> w>=1 (No0)
    const float Aw[3] = {r[2], r[0], r[1]};
    const float Bw[3] = {r[5], r[3], r[4]};
    float* part = ws + WS_PART;
#pragma unroll
    for (int b = 0; b < 3; ++b) {
      const int j0 = c * 9 + 0 * 3 + b, j1 = c * 9 + 3 + b, j2 = c * 9 + 6 + b;
      part[j0 * NCHUNK + chunk] = (chunk == 31) ? Bw[b] : Aw[b];  // kh=0: h<=510
      part[j1 * NCHUNK + chunk] = Aw[b];                          // kh=1
      part[j2 * NCHUNK + chunk] = (chunk == 0) ? Bw[b] : Aw[b];   // kh=2: h>=1
    }
  }
}

// ---------------------------------------------------------------------------
// Kernel 2 (1024 blocks x 256 thr = ONE block generation at 4/CU):
// issue row-0 loads, derive scale/sx/sw/rq once per block (hidden under the
// loads; identical FP ops per block -> deterministic), blocks 0..63 write wq,
// then 4 row-tiles of 64w x 64c: prefetch next row, quantize (interior
// no-clamp fast path), double-buffered LDS transpose (1 barrier/row).
// LDS ~37 KB -> 4 blocks/CU.
// ---------------------------------------------------------------------------
__global__ __launch_bounds__(256, 4) void k_fused(const float* __restrict__ in,
                                                  const float* __restrict__ wgt,
                                                  const float* __restrict__ ws,
                                                  float* __restrict__ out) {
  __shared__ float rq_s[KSZ];
  __shared__ float ldsT[2][64][68];   // double buffer: 1 barrier per row
  __shared__ float red[4][2];
  __shared__ float s_sx, s_sw;
  const int t = threadIdx.x;
  const int h0 = (blockIdx.x >> 3) << 2;   // 128 h-groups x 4 rows
  const int w0 = (blockIdx.x & 7) << 6;
  const int c = t >> 2;                    // 4 threads per channel
  const int fi = t & 3;

  // ---- issue row-0 loads first; prologue hides under them ----
  const float4* ibase = reinterpret_cast<const float4*>(
      in + (size_t)c * HW * HW + (size_t)h0 * HW + w0);
  float4 v0[4], v1[4];
#pragma unroll
  for (int k = 0; k < 4; ++k) v0[k] = ibase[fi + 4 * k];

  // ---- scale prologue (once per block; one generation -> paid once) ----
  float scale_r[3];
  float rxm = 0.f, rwm = 0.f;
#pragma unroll
  for (int rep = 0; rep < 3; ++rep) {
    const int j = t + rep * 256;
    if (j < KSZ) {
      const float4* pp = reinterpret_cast<const float4*>(ws + WS_PART + j * NCHUNK);
      float act = 0.f;
#pragma unroll
      for (int q = 0; q < NCHUNK / 4; ++q) {
        const float4 p = pp[q];
        act = fmaxf(act, fmaxf(fmaxf(p.x, p.y), fmaxf(p.z, p.w)));
      }
      const float wm = ws[WS_WMAX + j];
      float scale = sqrtf(act) / sqrtf(wm);   // alpha = 0.5
      if (scale == 0.f) scale = 1.f;
      scale_r[rep] = scale;
      rxm = fmaxf(rxm, act / scale);
      rwm = fmaxf(rwm, wm * scale);
    }
  }
#pragma unroll
  for (int m = 32; m >= 1; m >>= 1) {
    rxm = fmaxf(rxm, __shfl_xor(rxm, m));
    rwm = fmaxf(rwm, __shfl_xor(rwm, m));
  }
  if ((t & 63) == 0) { red[t >> 6][0] = rxm; red[t >> 6][1] = rwm; }
  __syncthreads();
  if (t == 0) {
    float mx = red[0][0], mw = red[0][1];
    for (int i = 1; i < 4; ++i) { mx = fmaxf(mx, red[i][0]); mw = fmaxf(mw, red[i][1]); }
    s_sx = (mx > 0.f) ? (mx / 127.f) : 1.f;
    s_sw = (mw > 0.f) ? (mw / 127.f) : 1.f;
  }
  __syncthreads();
  const float sx = s_sx, sw = s_sw;
#pragma unroll
  for (int rep = 0; rep < 3; ++rep) {
    const int j = t + rep * 256;
    if (j < KSZ) rq_s[j] = 1.f / (scale_r[rep] * sx);
  }
  __syncthreads();

  // ---- wq epilogue: blocks 0..63 each write one cout row ----
  if (blockIdx.x < 64) {
    const int co = blockIdx.x;
#pragma unroll
    for (int rep = 0; rep < 3; ++rep) {
      const int j = t + rep * 256;
      if (j < KSZ) {
        const int cc = j / 9;
        const int r = j - cc * 9;
        float u = (wgt[co * KSZ + j] * scale_r[rep]) / sw;
        u = fminf(fmaxf(u, -127.f), 127.f);
        out[co * KSZ + r * 64 + cc] = rintf(u) * sw;
      }
    }
  }

  float rq[9];
#pragma unroll
  for (int jq = 0; jq < 9; ++jq) rq[jq] = rq_s[c * 9 + jq];

  // ---- 4 row-tiles: pipelined loads, double-buffered LDS (1 barrier/row) ----
#pragma unroll
  for (int r = 0; r < 4; ++r) {
    if (r < 3) {
#pragma unroll
      for (int k = 0; k < 4; ++k) v1[k] = ibase[(r + 1) * 128 + fi + 4 * k];
    }
    const int h = h0 + r;
    const bool hb = (h == 0) || (h == 511);
    const int p = r & 1;
#pragma unroll
    for (int k = 0; k < 4; ++k) {
      const float4 v4 = v0[k];
      const int f4 = fi + 4 * k;
      const float vv[4] = {v4.x, v4.y, v4.z, v4.w};
#pragma unroll
      for (int i = 0; i < 4; ++i) {
        const int wl = f4 * 4 + i;
        const int w = w0 + wl;
        const float x = vv[i];
        float qs = 0.f;
#pragma unroll
        for (int jj = 0; jj < 9; ++jj) qs += rintf(x * rq[jj]);  // exact int sum
        if (hb || (w == 0) || (w == 511)) {                      // rare fix-up
          const bool hok0 = (h <= 510), hok2 = (h >= 1);
          const bool wok0 = (w <= 510), wok2 = (w >= 1);
          const bool ok[9] = {hok0 && wok0, hok0, hok0 && wok2,
                              wok0,         true, wok2,
                              hok2 && wok0, hok2, hok2 && wok2};
          qs = 0.f;
#pragma unroll
          for (int jj = 0; jj < 9; ++jj) {
            const float u = fminf(fmaxf(x * rq[jj], -127.f), 127.f);
            qs += ok[jj] ? rintf(u) : 0.f;
          }
        }
        ldsT[p][wl][c] = qs * sx;
      }
    }
    __syncthreads();     // buffer p complete; reuse of p ordered by next barrier
    float4* obase = reinterpret_cast<float4*>(
        out + XF_OFF + ((size_t)h * HW + w0) * 64);
#pragma unroll
    for (int k = 0; k < 4; ++k) {
      const int idx4 = k * 256 + t;        // 1024 float4 over [w_local][c]
      const int lw = idx4 >> 4;
      const int lc4 = idx4 & 15;
      obase[idx4] = *reinterpret_cast<const float4*>(&ldsT[p][lw][lc4 * 4]);
    }
#pragma unroll
    for (int k = 0; k < 4; ++k) v0[k] = v1[k];
  }
}

extern "C" void kernel_launch(void* const* d_in, const int* in_sizes, int n_in,
                              void* d_out, int out_size, void* d_ws, size_t ws_size,
                              hipStream_t stream) {
  (void)in_sizes; (void)n_in; (void)out_size; (void)ws_size;
  const float* in = reinterpret_cast<const float*>(d_in[0]);   // (1,64,512,512)
  const float* wgt = reinterpret_cast<const float*>(d_in[1]);  // (64,64,3,3)
  float* out = reinterpret_cast<float*>(d_out);                // wq | xf
  float* ws = reinterpret_cast<float*>(d_ws);

  k_pass1<<<dim3(2048 + 3), dim3(256), 0, stream>>>(in, wgt, ws);
  k_fused<<<dim3(1024), dim3(256), 0, stream>>>(in, wgt, ws, out);
}